// Round 1
// baseline (127.186 us; speedup 1.0000x reference)
//
#include <hip/hip_runtime.h>

#define K_CW 256
#define PPT 2       // points per thread (no split-K)

struct P8 { float4 a; float4 b; };  // {c0,c1,c2,c3} {csq,pad,pad,pad} -> one s_load_dwordx8

// Build packed codebook in ws. csq uses numpy rounding:
// ((c0*c0 + c1*c1) + c2*c2) + c3*c3  (sequential adds of rounded squares)
__global__ void vq_pack_kernel(const float* __restrict__ tlut, float* __restrict__ pk) {
    int k = threadIdx.x;  // 256 threads, 1 block
    float c0 = tlut[k * 4 + 0];
    float c1 = tlut[k * 4 + 1];
    float c2 = tlut[k * 4 + 2];
    float c3 = tlut[k * 4 + 3];
    float s = __fadd_rn(__fadd_rn(__fadd_rn(__fmul_rn(c0, c0), __fmul_rn(c1, c1)),
                                  __fmul_rn(c2, c2)),
                        __fmul_rn(c3, c3));
    pk[k * 8 + 0] = c0; pk[k * 8 + 1] = c1; pk[k * 8 + 2] = c2; pk[k * 8 + 3] = c3;
    pk[k * 8 + 4] = s;  pk[k * 8 + 5] = 0.f; pk[k * 8 + 6] = 0.f; pk[k * 8 + 7] = 0.f;
}

// One k-step for both points: exact numpy-rounded distance + first-occurrence argmin.
#define VQ_STEP(E, KIDX)                                                     \
    do {                                                                     \
        const float4 c_ = (E).a;                                             \
        const float cs_ = (E).b.x;                                           \
        _Pragma("unroll")                                                    \
        for (int i_ = 0; i_ < PPT; ++i_) {                                   \
            float cr_ = __fmul_rn(x0[i_], c_.x);                             \
            cr_ = __fmaf_rn(x1[i_], c_.y, cr_);                              \
            cr_ = __fmaf_rn(x2[i_], c_.z, cr_);                              \
            cr_ = __fmaf_rn(x3[i_], c_.w, cr_);                              \
            float t2_ = __fmaf_rn(-2.0f, cr_, xsq[i_]);                      \
            float d_ = __fadd_rn(t2_, cs_);                                  \
            besti[i_] = (d_ < bestd[i_]) ? (KIDX) : besti[i_];               \
            bestd[i_] = fminf(d_, bestd[i_]);                                \
        }                                                                    \
    } while (0)

__global__ __launch_bounds__(256, 8) void vq_argmin_kernel(
    const float* __restrict__ X,
    const float* __restrict__ tlut,
    const float* __restrict__ pk,
    float* __restrict__ outX,   // [B,4] reconstruction
    float* __restrict__ outS,   // [B] state, stored as float
    int B) {
    // No split-K: each thread scans all 256 codewords for PPT points.
    // 256-thr blocks, B/PPT threads total = 8192 waves = 32 waves/CU (full residency),
    // no LDS, no barrier, no merge.
    const int g = blockIdx.x * 256 + threadIdx.x;   // point-group id
    const int stride = B / PPT;                     // strided points -> coalesced

    const float4* __restrict__ X4 = reinterpret_cast<const float4*>(X);
    const float4* __restrict__ T4 = reinterpret_cast<const float4*>(tlut);
    const P8* __restrict__ PK = reinterpret_cast<const P8*>(pk);

    float x0[PPT], x1[PPT], x2[PPT], x3[PPT], xsq[PPT], bestd[PPT];
    int besti[PPT];

    #pragma unroll
    for (int i = 0; i < PPT; ++i) {
        const float4 xv = X4[g + i * stride];
        x0[i] = xv.x; x1[i] = xv.y; x2[i] = xv.z; x3[i] = xv.w;
        // x_sq with numpy rounding: sequential adds of rounded squares
        xsq[i] = __fadd_rn(__fadd_rn(__fadd_rn(__fmul_rn(xv.x, xv.x), __fmul_rn(xv.y, xv.y)),
                                     __fmul_rn(xv.z, xv.z)),
                           __fmul_rn(xv.w, xv.w));
        bestd[i] = __builtin_inff();
        besti[i] = 0;
    }

    // Double-buffered scalar staging: 2 x 4 P8 entries (~64 SGPRs in flight).
    // Codebook indices are wave-uniform -> s_load_dwordx8 through the constant cache;
    // each 4-entry load batch is covered by a 4k x PPT x 9 = 72-VALU compute phase.
    P8 b0[4], b1[4];
    #pragma unroll
    for (int j = 0; j < 4; ++j) b0[j] = PK[j];

    #pragma unroll 2
    for (int kk = 0; kk < K_CW; kk += 8) {
        #pragma unroll
        for (int j = 0; j < 4; ++j) b1[j] = PK[kk + 4 + j];
        #pragma unroll
        for (int j = 0; j < 4; ++j) VQ_STEP(b0[j], kk + j);
        #pragma unroll
        for (int j = 0; j < 4; ++j) b0[j] = PK[(kk + 8 + j) & (K_CW - 1)];  // wrap: last batch unused
        #pragma unroll
        for (int j = 0; j < 4; ++j) VQ_STEP(b1[j], kk + 4 + j);
    }

    #pragma unroll
    for (int i = 0; i < PPT; ++i) {
        const int p = g + i * stride;
        reinterpret_cast<float4*>(outX)[p] = T4[besti[i]];  // gather, tlut is L1-resident
        outS[p] = (float)besti[i];
    }
}

extern "C" void kernel_launch(void* const* d_in, const int* in_sizes, int n_in,
                              void* d_out, int out_size, void* d_ws, size_t ws_size,
                              hipStream_t stream) {
    const float* X    = (const float*)d_in[0];   // [B,4]
    const float* tlut = (const float*)d_in[1];   // [256,4]
    const int B = in_sizes[0] / 4;

    float* outX = (float*)d_out;          // first B*4 floats: hatX
    float* outS = outX + (size_t)B * 4;   // next B floats: state (as float)

    float* pk = (float*)d_ws;             // 256*8 floats packed codebook

    vq_pack_kernel<<<1, 256, 0, stream>>>(tlut, pk);

    const int groups = B / PPT;           // 524288 point-groups
    const int grid = groups / 256;        // 2048 blocks of 256 threads
    vq_argmin_kernel<<<grid, 256, 0, stream>>>(X, tlut, pk, outX, outS, B);
}

// Round 2
// 119.458 us; speedup vs baseline: 1.0647x; 1.0647x over previous
//
#include <hip/hip_runtime.h>

#define K_CW 256
#define PPT 2       // points per thread; B/PPT threads = 8192 waves = 32 waves/CU

// Single fused kernel. Codebook staged in LDS (broadcast reads, in-order DS
// returns -> compiler emits partial lgkmcnt waits and pipelines, unlike SMEM
// s_load which forces lgkmcnt(0) full drains).
__global__ __launch_bounds__(256, 8) void vq_argmin_kernel(
    const float* __restrict__ X,
    const float* __restrict__ tlut,
    float* __restrict__ outX,   // [B,4] reconstruction
    float* __restrict__ outS,   // [B] state, stored as float
    int B) {
    __shared__ float4 sc[K_CW];   // 4 KB: {c0,c1,c2,c3}
    __shared__ float  ss[K_CW];   // 1 KB: csq

    const int t = threadIdx.x;

    // Stage codebook: thread t owns codeword t. csq uses numpy rounding:
    // ((c0*c0 + c1*c1) + c2*c2) + c3*c3  (sequential adds of rounded squares)
    {
        const float4 cv = reinterpret_cast<const float4*>(tlut)[t];
        const float s = __fadd_rn(__fadd_rn(__fadd_rn(__fmul_rn(cv.x, cv.x),
                                                      __fmul_rn(cv.y, cv.y)),
                                            __fmul_rn(cv.z, cv.z)),
                                  __fmul_rn(cv.w, cv.w));
        sc[t] = cv;
        ss[t] = s;
    }

    const int g = blockIdx.x * 256 + t;   // point-group id
    const int stride = B / PPT;           // strided points -> coalesced

    const float4* __restrict__ X4 = reinterpret_cast<const float4*>(X);

    float x0[PPT], x1[PPT], x2[PPT], x3[PPT], xsq[PPT], bestd[PPT];
    int besti[PPT];

    #pragma unroll
    for (int i = 0; i < PPT; ++i) {
        const float4 xv = X4[g + i * stride];
        x0[i] = xv.x; x1[i] = xv.y; x2[i] = xv.z; x3[i] = xv.w;
        // x_sq with numpy rounding: sequential adds of rounded squares
        xsq[i] = __fadd_rn(__fadd_rn(__fadd_rn(__fmul_rn(xv.x, xv.x), __fmul_rn(xv.y, xv.y)),
                                     __fmul_rn(xv.z, xv.z)),
                           __fmul_rn(xv.w, xv.w));
        bestd[i] = __builtin_inff();
        besti[i] = 0;
    }

    __syncthreads();

    // Main scan: all 256 codewords, ascending k, strict '<' -> np.argmin
    // first-occurrence. Uniform LDS address -> hardware broadcast, 0 conflicts.
    // unroll 8: ~8*5 staged VGPRs for in-flight c/cs + state fits under the
    // 64-VGPR / 8-waves-per-EU budget enforced by launch_bounds.
    #pragma unroll 8
    for (int k = 0; k < K_CW; ++k) {
        const float4 c = sc[k];
        const float cs = ss[k];
        #pragma unroll
        for (int i = 0; i < PPT; ++i) {
            // cross: numpy einsum `accum += a*b` with fp-contract -> ascending FMA chain
            float cross = __fmul_rn(x0[i], c.x);
            cross = __fmaf_rn(x1[i], c.y, cross);
            cross = __fmaf_rn(x2[i], c.z, cross);
            cross = __fmaf_rn(x3[i], c.w, cross);
            // (x_sq - 2*cross) + c_sq ; fma(-2,cross,xsq) == rn(xsq - rn(2*cross)) exactly
            float t2 = __fmaf_rn(-2.0f, cross, xsq[i]);
            float d = __fadd_rn(t2, cs);
            // argmin, first occurrence (strict <), ascending k:
            besti[i] = (d < bestd[i]) ? k : besti[i];
            bestd[i] = fminf(d, bestd[i]);
        }
    }

    #pragma unroll
    for (int i = 0; i < PPT; ++i) {
        const int p = g + i * stride;
        reinterpret_cast<float4*>(outX)[p] = sc[besti[i]];  // gather from LDS
        outS[p] = (float)besti[i];
    }
}

extern "C" void kernel_launch(void* const* d_in, const int* in_sizes, int n_in,
                              void* d_out, int out_size, void* d_ws, size_t ws_size,
                              hipStream_t stream) {
    const float* X    = (const float*)d_in[0];   // [B,4]
    const float* tlut = (const float*)d_in[1];   // [256,4]
    const int B = in_sizes[0] / 4;

    float* outX = (float*)d_out;          // first B*4 floats: hatX
    float* outS = outX + (size_t)B * 4;   // next B floats: state (as float)

    const int groups = B / PPT;           // 524288 point-groups
    const int grid = groups / 256;        // 2048 blocks of 256 threads
    vq_argmin_kernel<<<grid, 256, 0, stream>>>(X, tlut, outX, outS, B);
}